// Round 11
// baseline (110.957 us; speedup 1.0000x reference)
//
#include <hip/hip_runtime.h>
#include <cstdint>

// B=4, N=256, D=128, HID=128, IN_DIM=516.
// acc[p,h] = [|hi-hj|;hi*hj] @ W1[256:512]*256  (8 shared fp8 ks)  -- symmetric
//          + 16*onehot(ii,jj) @ (PiB'/16, Pjf'/16)  (1 extra ks per direction)
// pre'_d = acc_d + scal_d(p)·(W1[512:516]*256) ; L_d = relu(pre')@(W2/256)+b2
// out[i,j]=out[j,i]=0.5*(L_f+L_m) ; diag -1e9.
// R11 = R10 with dpp ctrl as template arg (compile fix).

typedef float f32x4 __attribute__((ext_vector_type(4)));

#define INV256 0.00390625f

__device__ __forceinline__ uint32_t pk4(float a, float b, float c, float d) {
  uint32_t u = __builtin_amdgcn_cvt_pk_fp8_f32(a, b, 0, false);
  u = __builtin_amdgcn_cvt_pk_fp8_f32(c, d, u, true);
  return u;
}
__device__ __forceinline__ long mk64(uint32_t lo, uint32_t hi) {
  return (long)((((unsigned long long)hi) << 32) | lo);
}
template <int CTRL>
__device__ __forceinline__ float dppadd(float v) {
  return v + __builtin_bit_cast(float, __builtin_amdgcn_update_dpp(
                 0, __builtin_bit_cast(int, v), CTRL, 0xF, 0xF, true));
}
// full 16-lane (row) sum: quad butterfly then cyclic quad-combine
__device__ __forceinline__ float rowsum16(float v) {
  v = dppadd<0xB1>(v);   // quad_perm xor1
  v = dppadd<0x4E>(v);   // quad_perm xor2
  v = dppadd<0x124>(v);  // row_ror:4
  v = dppadd<0x128>(v);  // row_ror:8
  return v;
}
// one-hot fp8 fragment words: 16.0 (0x58) at byte position x in [0,8)
__device__ __forceinline__ uint2 onehot8(int x) {
  uint2 u;
  u.x = (x < 4) ? (0x58u << (x * 8)) : 0u;
  u.y = (x >= 4) ? (0x58u << ((x - 4) * 8)) : 0u;
  return u;
}

// bid<32 (tid<128): pack fp8 B-image (lane-linear MFMA fragment order, W x256)
// bid in [32,288): 4 rows/block: PiB' = 256*(node@W1[0:128]+b1); Pjf' = 256*(node@W1[128:256])
__global__ __launch_bounds__(256) void pre_k(const float* __restrict__ node,
                                             const float* __restrict__ W1,
                                             const float* __restrict__ b1,
                                             float* __restrict__ PiB,
                                             float* __restrict__ Pjf,
                                             uint32_t* __restrict__ W1f8) {
  int bid = blockIdx.x;
  int tid = threadIdx.x;
  if (bid < 32) {
    if (tid < 128) {
      int ks = bid >> 2, nip = (bid >> 1) & 1, wn = bid & 1;
      int lane = tid & 63, nilow = tid >> 6;
      int quad = lane >> 4, col = lane & 15;
      int h = wn * 64 + (nip * 2 + nilow) * 16 + col;
      int k0 = ks * 32 + quad * 8;
      float w[8];
#pragma unroll
      for (int t = 0; t < 8; ++t) w[t] = W1[(256 + k0 + t) * 128 + h] * 256.0f;
      uint2 u;
      u.x = pk4(w[0], w[1], w[2], w[3]);
      u.y = pk4(w[4], w[5], w[6], w[7]);
      reinterpret_cast<uint2*>(W1f8)[(bid * 64 + lane) * 2 + nilow] = u;
    }
    return;
  }
  __shared__ float sN[512];  // [d][r] transposed, 128 x 4
  const int r0 = (bid - 32) * 4;
  {
    int d = tid & 127, rh = tid >> 7;
#pragma unroll
    for (int rr = 0; rr < 2; ++rr) {
      int row = rr * 2 + rh;
      sN[d * 4 + row] = node[(size_t)(r0 + row) * 128 + d];
    }
  }
  __syncthreads();
  const int h = tid & 127, proj = tid >> 7;
  const float* Wp = W1 + (size_t)proj * 128 * 128 + h;
  float a0 = 0.f, a1 = 0.f, a2 = 0.f, a3 = 0.f;
#pragma unroll 4
  for (int d = 0; d < 128; ++d) {
    float w = Wp[(size_t)d * 128];
    float4 v = *reinterpret_cast<const float4*>(&sN[d * 4]);
    a0 = fmaf(v.x, w, a0);
    a1 = fmaf(v.y, w, a1);
    a2 = fmaf(v.z, w, a2);
    a3 = fmaf(v.w, w, a3);
  }
  float bb = (proj == 0) ? b1[h] : 0.f;
  float* dst = (proj == 0) ? PiB : Pjf;
  dst[(size_t)(r0 + 0) * 128 + h] = 256.f * (a0 + bb);
  dst[(size_t)(r0 + 1) * 128 + h] = 256.f * (a1 + bb);
  dst[(size_t)(r0 + 2) * 128 + h] = 256.f * (a2 + bb);
  dst[(size_t)(r0 + 3) * 128 + h] = 256.f * (a3 + bb);
}

// grid 2112 = b(4) * 528 unordered 8-group pairs (I<=J). 64 pairs/block, K=256+32 fp8.
__global__ __launch_bounds__(256, 6) void main_k(
    const float* __restrict__ node, const float* __restrict__ baseL,
    const float* __restrict__ compL, const float* __restrict__ W1,
    const float* __restrict__ W2, const float* __restrict__ b2,
    const uint32_t* __restrict__ W1f8, const float* __restrict__ PiB,
    const float* __restrict__ Pjf, float* __restrict__ out) {
  // sF: [ks 0..7][mi][q][scol] 8B fp8 A-image, scol=(colp+2q+4(ks&3))&15 -> 16384 B
  // sScal: [64 p][12] fp32 {fwd bl',sg',cl',sg' | mir ...} (stride 12, 16B-aligned)
  // sP: [dir 2][64 p][4 wave] fp32 partials -- own buffer (no overlay hazard)
  __shared__ __align__(16) char sF[16384];
  __shared__ __align__(16) float sScal[64 * 12];
  __shared__ __align__(16) float sP[512];

  const int tid = threadIdx.x;
  const int bx = blockIdx.x;
  const int b = bx / 528;
  const int t = bx - b * 528;
  int tI = (int)((65.0f - sqrtf(4225.0f - 8.0f * (float)t)) * 0.5f);
  tI = (tI < 0) ? 0 : (tI > 31 ? 31 : tI);
  while (((65 * tI - tI * tI) >> 1) > t) --tI;
  while (tI < 31 && ((65 * (tI + 1) - (tI + 1) * (tI + 1)) >> 1) <= t) ++tI;
  const int tJ = tI + (t - ((65 * tI - tI * tI) >> 1));
  const int I0 = tI * 8, J0 = tJ * 8;
  const int rowB = b * 256;

  const int lane = tid & 63;
  const int wn2 = tid >> 6;  // wave owns h in [wn2*32, wn2*32+32)
  const int col = lane & 15, quad = lane >> 4;

  // ---- extra-slice B fragments: one-hot coefficients = PiB'/16, Pjf'/16 rows ----
  // k0-7 (quad0) <-> I-group rows: fwd=PiB', mir=Pjf' ; k8-15 (quad1) <-> J-group:
  // fwd=Pjf', mir=PiB' ; quads 2/3 zero.
  uint2 xBF[2] = {}, xBM[2] = {};
  if (quad < 2) {
    const size_t offI = (size_t)(rowB + I0) * 128;
    const size_t offJ = (size_t)(rowB + J0) * 128;
    const float* fA = (quad == 0) ? (PiB + offI) : (Pjf + offJ);
    const float* mA = (quad == 0) ? (Pjf + offI) : (PiB + offJ);
#pragma unroll
    for (int ni = 0; ni < 2; ++ni) {
      int h = (wn2 * 2 + ni) * 16 + col;
      float f[8], m[8];
#pragma unroll
      for (int tt = 0; tt < 8; ++tt) {
        f[tt] = fA[tt * 128 + h] * 0.0625f;
        m[tt] = mA[tt * 128 + h] * 0.0625f;
      }
      xBF[ni].x = pk4(f[0], f[1], f[2], f[3]);
      xBF[ni].y = pk4(f[4], f[5], f[6], f[7]);
      xBM[ni].x = pk4(m[0], m[1], m[2], m[3]);
      xBM[ni].y = pk4(m[4], m[5], m[6], m[7]);
    }
  }

  // ---- stage scal (x256) fp32: fwd (tid<64) and mirror (tid in [64,128)) ----
  if (tid < 128) {
    int p = tid & 63, dir = tid >> 6;
    int iN = I0 + (p >> 3), jN = J0 + (p & 7);
    int rr = dir ? jN : iN, cc = dir ? iN : jN;
    float bl = fminf(fmaxf(baseL[(size_t)(rowB + rr) * 256 + cc], -20.f), 20.f);
    float cl = fminf(fmaxf(compL[(size_t)(rowB + rr) * 256 + cc], -20.f), 20.f);
    float4 v;
    v.x = 256.f * bl;
    v.y = 256.f / (1.f + __expf(-bl));
    v.z = 256.f * cl;
    v.w = 256.f / (1.f + __expf(-cl));
    *reinterpret_cast<float4*>(&sScal[p * 12 + dir * 4]) = v;
  }

  // ---- per-lane epilogue constants ----
  float cB0[2], cB1[2], cB2[2], cB3[2], cW2[2];
#pragma unroll
  for (int ni = 0; ni < 2; ++ni) {
    int h = (wn2 * 2 + ni) * 16 + col;
    cB0[ni] = W1[512 * 128 + h];
    cB1[ni] = W1[513 * 128 + h];
    cB2[ni] = W1[514 * 128 + h];
    cB3[ni] = W1[515 * 128 + h];
    cW2[ni] = W2[h] * INV256;
  }
  const float b2v = b2[0];

  // ---- F-build: 64 pairs x 256 k fp8, node direct from global (L1/L2-hot) ----
  {
    const int d4 = tid & 31;
    const int rr = tid >> 5;  // j-row 0..7
    const int ks1 = d4 >> 3, qd = (d4 >> 1) & 3, kb = (d4 & 1) * 4;
    const int scolbase = 2 * qd + 4 * ks1;
    const float4 hj =
        *reinterpret_cast<const float4*>(node + (size_t)(rowB + J0 + rr) * 128 + d4 * 4);
#pragma unroll
    for (int ii = 0; ii < 8; ++ii) {
      const float4 hi =
          *reinterpret_cast<const float4*>(node + (size_t)(rowB + I0 + ii) * 128 + d4 * 4);
      uint32_t du = pk4(fabsf(hi.x - hj.x), fabsf(hi.y - hj.y),
                        fabsf(hi.z - hj.z), fabsf(hi.w - hj.w));
      uint32_t pu = pk4(hi.x * hj.x, hi.y * hj.y, hi.z * hj.z, hi.w * hj.w);
      int p = ii * 8 + rr;
      int colp = p & 15, mi = p >> 4;
      int scol = (colp + scolbase) & 15;
      uint32_t addr = mi * 512 + qd * 128 + scol * 8 + kb;
      *reinterpret_cast<uint32_t*>(sF + ks1 * 2048 + addr) = du;
      *reinterpret_cast<uint32_t*>(sF + (ks1 + 4) * 2048 + addr) = pu;
    }
  }
  __syncthreads();  // barrier 1 (sF + sScal ready)

  // ---- MFMA: 8 shared ks (B streamed from global/L2) ----
  const uint4* Bg = reinterpret_cast<const uint4*>(W1f8);
  const int uB = ((wn2 & 1) << 1) | (wn2 >> 1);
  f32x4 acc[4][2] = {};
#pragma unroll
  for (int ks = 0; ks < 8; ++ks) {
    uint4 bv = Bg[(ks * 4 + uB) * 64 + lane];
    long bb0 = mk64(bv.x, bv.y);
    long bb1 = mk64(bv.z, bv.w);
    const int ascol = (col + 2 * quad + 4 * (ks & 3)) & 15;
    const char* aks = sF + ks * 2048 + quad * 128 + ascol * 8;
#pragma unroll
    for (int mi = 0; mi < 4; ++mi) {
      uint2 av = *reinterpret_cast<const uint2*>(aks + mi * 512);
      long aa = mk64(av.x, av.y);
      acc[mi][0] = __builtin_amdgcn_mfma_f32_16x16x32_fp8_fp8(aa, bb0, acc[mi][0], 0, 0, 0);
      acc[mi][1] = __builtin_amdgcn_mfma_f32_16x16x32_fp8_fp8(aa, bb1, acc[mi][1], 0, 0, 0);
    }
  }

  // ---- extra slice, FWD: acc += onehotA · B_f ----
  const int jj = col & 7;
  const uint2 axj = onehot8(jj);
  const long xbf0 = mk64(xBF[0].x, xBF[0].y), xbf1 = mk64(xBF[1].x, xBF[1].y);
#pragma unroll
  for (int mi = 0; mi < 4; ++mi) {
    uint2 axi = onehot8(mi * 2 + (col >> 3));
    uint2 ax = (quad == 0) ? axi : ((quad == 1) ? axj : make_uint2(0u, 0u));
    long aa = mk64(ax.x, ax.y);
    acc[mi][0] = __builtin_amdgcn_mfma_f32_16x16x32_fp8_fp8(aa, xbf0, acc[mi][0], 0, 0, 0);
    acc[mi][1] = __builtin_amdgcn_mfma_f32_16x16x32_fp8_fp8(aa, xbf1, acc[mi][1], 0, 0, 0);
  }

  // ---- epilogue FWD ----
#pragma unroll
  for (int mi = 0; mi < 4; ++mi) {
#pragma unroll
    for (int r = 0; r < 4; ++r) {
      int p = mi * 16 + quad * 4 + r;
      float4 sc = *reinterpret_cast<const float4*>(&sScal[p * 12]);
      float v = 0.f;
#pragma unroll
      for (int ni = 0; ni < 2; ++ni) {
        float pre = fmaf(sc.x, cB0[ni], acc[mi][ni][r]);
        pre = fmaf(sc.y, cB1[ni], pre);
        pre = fmaf(sc.z, cB2[ni], pre);
        pre = fmaf(sc.w, cB3[ni], pre);
        v = fmaf(fmaxf(pre, 0.f), cW2[ni], v);
      }
      v = rowsum16(v);
      if (col == 0) sP[p * 4 + wn2] = v;
    }
  }

  // ---- flip to MIRROR: acc += onehotA·(-B_f) + onehotA·B_m ----
  const long xbf0n = mk64(xBF[0].x ^ 0x80808080u, xBF[0].y ^ 0x80808080u);
  const long xbf1n = mk64(xBF[1].x ^ 0x80808080u, xBF[1].y ^ 0x80808080u);
  const long xbm0 = mk64(xBM[0].x, xBM[0].y), xbm1 = mk64(xBM[1].x, xBM[1].y);
#pragma unroll
  for (int mi = 0; mi < 4; ++mi) {
    uint2 axi = onehot8(mi * 2 + (col >> 3));
    uint2 ax = (quad == 0) ? axi : ((quad == 1) ? axj : make_uint2(0u, 0u));
    long aa = mk64(ax.x, ax.y);
    acc[mi][0] = __builtin_amdgcn_mfma_f32_16x16x32_fp8_fp8(aa, xbf0n, acc[mi][0], 0, 0, 0);
    acc[mi][1] = __builtin_amdgcn_mfma_f32_16x16x32_fp8_fp8(aa, xbf1n, acc[mi][1], 0, 0, 0);
    acc[mi][0] = __builtin_amdgcn_mfma_f32_16x16x32_fp8_fp8(aa, xbm0, acc[mi][0], 0, 0, 0);
    acc[mi][1] = __builtin_amdgcn_mfma_f32_16x16x32_fp8_fp8(aa, xbm1, acc[mi][1], 0, 0, 0);
  }

  // ---- epilogue MIRROR ----
#pragma unroll
  for (int mi = 0; mi < 4; ++mi) {
#pragma unroll
    for (int r = 0; r < 4; ++r) {
      int p = mi * 16 + quad * 4 + r;
      float4 sc = *reinterpret_cast<const float4*>(&sScal[p * 12 + 4]);
      float v = 0.f;
#pragma unroll
      for (int ni = 0; ni < 2; ++ni) {
        float pre = fmaf(sc.x, cB0[ni], acc[mi][ni][r]);
        pre = fmaf(sc.y, cB1[ni], pre);
        pre = fmaf(sc.z, cB2[ni], pre);
        pre = fmaf(sc.w, cB3[ni], pre);
        v = fmaf(fmaxf(pre, 0.f), cW2[ni], v);
      }
      v = rowsum16(v);
      if (col == 0) sP[256 + p * 4 + wn2] = v;
    }
  }
  __syncthreads();  // barrier 2

  // ---- final: combine 4+4 wave-partials, symmetric store ----
  if (tid < 64) {
    int p = tid;
    int pii = p >> 3, pjj = p & 7;
    if (!(tI == tJ && pii > pjj)) {  // diagonal blocks: mirror pair covers it
      float4 f4 = *reinterpret_cast<const float4*>(&sP[p * 4]);
      float4 m4 = *reinterpret_cast<const float4*>(&sP[256 + p * 4]);
      float val = 0.5f * ((f4.x + f4.y + f4.z + f4.w) + (m4.x + m4.y + m4.z + m4.w)) + b2v;
      int iN = I0 + pii, jN = J0 + pjj;
      if (iN == jN) {
        out[(size_t)(rowB + iN) * 256 + jN] = -1e9f;
      } else {
        out[(size_t)(rowB + iN) * 256 + jN] = val;
        out[(size_t)(rowB + jN) * 256 + iN] = val;
      }
    }
  }
}

extern "C" void kernel_launch(void* const* d_in, const int* in_sizes, int n_in,
                              void* d_out, int out_size, void* d_ws, size_t ws_size,
                              hipStream_t stream) {
  const float* node = (const float*)d_in[0];   // [4,256,128]
  const float* baseL = (const float*)d_in[1];  // [4,256,256]
  const float* compL = (const float*)d_in[2];  // [4,256,256]
  const float* W1 = (const float*)d_in[3];     // [516,128]
  const float* b1 = (const float*)d_in[4];     // [128]
  const float* W2 = (const float*)d_in[5];     // [128,1]
  const float* b2 = (const float*)d_in[6];     // [1]
  float* out = (float*)d_out;                  // [4,256,256] fp32

  char* ws = (char*)d_ws;
  float* PiB = (float*)(ws);                        // 512 KB
  float* Pjf = (float*)(ws + (512 << 10));          // 512 KB
  uint32_t* W1f8 = (uint32_t*)(ws + (1024 << 10));  // 32 KB

  pre_k<<<288, 256, 0, stream>>>(node, W1, b1, PiB, Pjf, W1f8);
  main_k<<<2112, 256, 0, stream>>>(node, baseL, compL, W1, W2, b2, W1f8, PiB, Pjf, out);
}

// Round 12
// 96.310 us; speedup vs baseline: 1.1521x; 1.1521x over previous
//
#include <hip/hip_runtime.h>
#include <cstdint>

// B=4, N=256, D=128, HID=128, IN_DIM=516.
// G[i,j,h] = [|hi-hj| ; hi*hj] @ W1[256:512]  (K=256 fp8 MFMA, W x256) -- symmetric in (i,j)
// pre' = 256*pre = acc + PiB'[i,h] + Pjf'[j,h] + scal'(i,j)·w   (all pre-scaled x256)
// L = relu(pre') @ (W2/256) + b2 ; out[i,j]=out[j,i]=0.5*(L_f+L_m) ; diag -1e9.
// R12 = best-of(R8,R9): bf16 sScal (R8), DPP reduce + batched pre_k (R9),
//       in-loop B loads, LDS 25.9KB + LB(256,6) -> 6 blocks/CU (24 waves).
//       (R11's one-hot fold spilled: VGPR=40 + 45MB scratch writes -- reverted.)

typedef float f32x4 __attribute__((ext_vector_type(4)));

#define INV256 0.00390625f

__device__ __forceinline__ uint32_t pk4(float a, float b, float c, float d) {
  uint32_t u = __builtin_amdgcn_cvt_pk_fp8_f32(a, b, 0, false);
  u = __builtin_amdgcn_cvt_pk_fp8_f32(c, d, u, true);
  return u;
}
__device__ __forceinline__ uint32_t pkbf2(float lo, float hi) {
  uint32_t l = __builtin_bit_cast(uint32_t, lo);
  uint32_t h = __builtin_bit_cast(uint32_t, hi);
  return (l >> 16) | (h & 0xffff0000u);
}
__device__ __forceinline__ float ulo(uint32_t u) {
  return __builtin_bit_cast(float, u << 16);
}
__device__ __forceinline__ float uhi(uint32_t u) {
  return __builtin_bit_cast(float, u & 0xffff0000u);
}
__device__ __forceinline__ long mk64(uint32_t lo, uint32_t hi) {
  return (long)((((unsigned long long)hi) << 32) | lo);
}
template <int CTRL>
__device__ __forceinline__ float dppadd(float v) {
  return v + __builtin_bit_cast(float, __builtin_amdgcn_update_dpp(
                 0, __builtin_bit_cast(int, v), CTRL, 0xF, 0xF, true));
}
__device__ __forceinline__ float qsum4(float v) {
  v = dppadd<0xB1>(v);  // quad_perm xor1
  v = dppadd<0x4E>(v);  // quad_perm xor2
  return v;
}

// bid<32 (tid<128): pack fp8 B-image (lane-linear MFMA fragment order, W x256)
// bid in [32,288): 4 rows/block: PiB' = 256*(node@W1[0:128]+b1); Pjf' = 256*(node@W1[128:256])
__global__ __launch_bounds__(256) void pre_k(const float* __restrict__ node,
                                             const float* __restrict__ W1,
                                             const float* __restrict__ b1,
                                             float* __restrict__ PiB,
                                             float* __restrict__ Pjf,
                                             uint32_t* __restrict__ W1f8) {
  int bid = blockIdx.x;
  int tid = threadIdx.x;
  if (bid < 32) {
    if (tid < 128) {
      int ks = bid >> 2, nip = (bid >> 1) & 1, wn = bid & 1;
      int lane = tid & 63, nilow = tid >> 6;
      int quad = lane >> 4, col = lane & 15;
      int h = wn * 64 + (nip * 2 + nilow) * 16 + col;
      int k0 = ks * 32 + quad * 8;
      float w[8];
#pragma unroll
      for (int t = 0; t < 8; ++t) w[t] = W1[(256 + k0 + t) * 128 + h] * 256.0f;
      uint2 u;
      u.x = pk4(w[0], w[1], w[2], w[3]);
      u.y = pk4(w[4], w[5], w[6], w[7]);
      reinterpret_cast<uint2*>(W1f8)[(bid * 64 + lane) * 2 + nilow] = u;
    }
    return;
  }
  __shared__ float sN[512];  // [d][r] transposed, 128 x 4
  const int r0 = (bid - 32) * 4;
  {
    int d = tid & 127, rh = tid >> 7;
#pragma unroll
    for (int rr = 0; rr < 2; ++rr) {
      int row = rr * 2 + rh;
      sN[d * 4 + row] = node[(size_t)(r0 + row) * 128 + d];
    }
  }
  __syncthreads();
  const int h = tid & 127, proj = tid >> 7;
  const float* Wp = W1 + (size_t)proj * 128 * 128 + h;
  float a0 = 0.f, a1 = 0.f, a2 = 0.f, a3 = 0.f;
#pragma unroll 4
  for (int d = 0; d < 128; ++d) {
    float w = Wp[(size_t)d * 128];
    float4 v = *reinterpret_cast<const float4*>(&sN[d * 4]);
    a0 = fmaf(v.x, w, a0);
    a1 = fmaf(v.y, w, a1);
    a2 = fmaf(v.z, w, a2);
    a3 = fmaf(v.w, w, a3);
  }
  float bb = (proj == 0) ? b1[h] : 0.f;
  float* dst = (proj == 0) ? PiB : Pjf;
  dst[(size_t)(r0 + 0) * 128 + h] = 256.f * (a0 + bb);
  dst[(size_t)(r0 + 1) * 128 + h] = 256.f * (a1 + bb);
  dst[(size_t)(r0 + 2) * 128 + h] = 256.f * (a2 + bb);
  dst[(size_t)(r0 + 3) * 128 + h] = 256.f * (a3 + bb);
}

// grid 2112 = b(4) * 528 unordered 8-group pairs (I<=J). 64 pairs/block, K=256 fp8.
__global__ __launch_bounds__(256, 6) void main_k(
    const float* __restrict__ node, const float* __restrict__ baseL,
    const float* __restrict__ compL, const float* __restrict__ W1,
    const float* __restrict__ W2, const float* __restrict__ b2,
    const uint32_t* __restrict__ W1f8, const float* __restrict__ PiB,
    const float* __restrict__ Pjf, float* __restrict__ out) {
  // sF: [ks 0..7][mi][q][scol] 8B fp8 A-image, scol=(colp+2q+4(ks&3))&15 -> 16384 B
  //   overlaid post-MFMA by sP: [64 pairs][42] fp32 (fwd @0..15, mirror @20..35)
  // sPP: [16 rows][132] u32 {bf16 PiB' | bf16 Pjf'} (rows 0-7 I-group, 8-15 J-group)
  // sScal: [64 pairs] uint4 bf16x2 {bl',sg'}{cl',sg'} fwd (.x,.y) + mirror (.z,.w)
  // total 16384 + 8448 + 1024 = 25856 B -> 6 blocks/CU at LB(256,6)
  __shared__ __align__(16) char sF[16384];
  __shared__ __align__(16) uint32_t sPP[16 * 132];
  __shared__ __align__(16) uint4 sScal[64];
  float* sP = reinterpret_cast<float*>(sF);  // overlay

  const int tid = threadIdx.x;
  const int bx = blockIdx.x;
  const int b = bx / 528;
  const int t = bx - b * 528;
  int tI = (int)((65.0f - sqrtf(4225.0f - 8.0f * (float)t)) * 0.5f);
  tI = (tI < 0) ? 0 : (tI > 31 ? 31 : tI);
  while (((65 * tI - tI * tI) >> 1) > t) --tI;
  while (tI < 31 && ((65 * (tI + 1) - (tI + 1) * (tI + 1)) >> 1) <= t) ++tI;
  const int tJ = tI + (t - ((65 * tI - tI * tI) >> 1));
  const int I0 = tI * 8, J0 = tJ * 8;
  const int rowB = b * 256;

  const int lane = tid & 63;
  const int wn2 = tid >> 6;  // wave owns h in [wn2*32, wn2*32+32)
  const int col = lane & 15, quad = lane >> 4;

  // ---- stage sPP: 16 rows x 128 u32 {PiB'|Pjf'} bf16-packed, coalesced ----
#pragma unroll
  for (int it = 0; it < 2; ++it) {
    int fidx = it * 256 + tid;  // 512 float4 slots
    int row = fidx >> 5, d4 = fidx & 31;
    int gr = rowB + ((row < 8) ? (I0 + row) : (J0 + row - 8));
    float4 a = reinterpret_cast<const float4*>(PiB + (size_t)gr * 128)[d4];
    float4 c = reinterpret_cast<const float4*>(Pjf + (size_t)gr * 128)[d4];
    uint4 u;
    u.x = pkbf2(a.x, c.x);
    u.y = pkbf2(a.y, c.y);
    u.z = pkbf2(a.z, c.z);
    u.w = pkbf2(a.w, c.w);
    *reinterpret_cast<uint4*>(&sPP[row * 132 + d4 * 4]) = u;
  }

  // ---- stage scal (x256) bf16-packed: fwd (tid<64) and mirror (tid in [64,128)) ----
  if (tid < 128) {
    int p = tid & 63, dir = tid >> 6;
    int iN = I0 + (p >> 3), jN = J0 + (p & 7);
    int rr = dir ? jN : iN, cc = dir ? iN : jN;
    float bl = fminf(fmaxf(baseL[(size_t)(rowB + rr) * 256 + cc], -20.f), 20.f);
    float cl = fminf(fmaxf(compL[(size_t)(rowB + rr) * 256 + cc], -20.f), 20.f);
    uint2 u;
    u.x = pkbf2(256.f * bl, 256.f / (1.f + __expf(-bl)));
    u.y = pkbf2(256.f * cl, 256.f / (1.f + __expf(-cl)));
    *reinterpret_cast<uint2*>(reinterpret_cast<char*>(&sScal[p]) + dir * 8) = u;
  }

  // ---- per-lane epilogue constants (2 ni columns) ----
  float cB0[2], cB1[2], cB2[2], cB3[2], cW2[2];
#pragma unroll
  for (int ni = 0; ni < 2; ++ni) {
    int h = (wn2 * 2 + ni) * 16 + col;
    cB0[ni] = W1[512 * 128 + h];
    cB1[ni] = W1[513 * 128 + h];
    cB2[ni] = W1[514 * 128 + h];
    cB3[ni] = W1[515 * 128 + h];
    cW2[ni] = W2[h] * INV256;
  }
  const float b2v = b2[0];

  // ---- F-build: 64 pairs x 256 k fp8, node direct from global (L1/L2-hot) ----
  {
    const int d4 = tid & 31;
    const int rr = tid >> 5;  // j-row 0..7
    const int ks1 = d4 >> 3, qd = (d4 >> 1) & 3, kb = (d4 & 1) * 4;
    const int scolbase = 2 * qd + 4 * ks1;
    const float4 hj =
        *reinterpret_cast<const float4*>(node + (size_t)(rowB + J0 + rr) * 128 + d4 * 4);
#pragma unroll
    for (int ii = 0; ii < 8; ++ii) {
      const float4 hi =
          *reinterpret_cast<const float4*>(node + (size_t)(rowB + I0 + ii) * 128 + d4 * 4);
      uint32_t du = pk4(fabsf(hi.x - hj.x), fabsf(hi.y - hj.y),
                        fabsf(hi.z - hj.z), fabsf(hi.w - hj.w));
      uint32_t pu = pk4(hi.x * hj.x, hi.y * hj.y, hi.z * hj.z, hi.w * hj.w);
      int p = ii * 8 + rr;
      int colp = p & 15, mi = p >> 4;
      int scol = (colp + scolbase) & 15;
      uint32_t addr = mi * 512 + qd * 128 + scol * 8 + kb;
      *reinterpret_cast<uint32_t*>(sF + ks1 * 2048 + addr) = du;
      *reinterpret_cast<uint32_t*>(sF + (ks1 + 4) * 2048 + addr) = pu;
    }
  }
  __syncthreads();  // barrier 1

  // ---- MFMA: acc[4 mi][2 ni], K=256; A swizzled LDS, B in-loop from L2 ----
  const uint4* Bg = reinterpret_cast<const uint4*>(W1f8);
  const int uB = ((wn2 & 1) << 1) | (wn2 >> 1);
  f32x4 acc[4][2] = {};
#pragma unroll
  for (int ks = 0; ks < 8; ++ks) {
    uint4 bv = Bg[(ks * 4 + uB) * 64 + lane];
    long bb0 = mk64(bv.x, bv.y);
    long bb1 = mk64(bv.z, bv.w);
    const int ascol = (col + 2 * quad + 4 * (ks & 3)) & 15;
    const char* aks = sF + ks * 2048 + quad * 128 + ascol * 8;
#pragma unroll
    for (int mi = 0; mi < 4; ++mi) {
      uint2 av = *reinterpret_cast<const uint2*>(aks + mi * 512);
      long aa = mk64(av.x, av.y);
      acc[mi][0] = __builtin_amdgcn_mfma_f32_16x16x32_fp8_fp8(aa, bb0, acc[mi][0], 0, 0, 0);
      acc[mi][1] = __builtin_amdgcn_mfma_f32_16x16x32_fp8_fp8(aa, bb1, acc[mi][1], 0, 0, 0);
    }
  }
  __syncthreads();  // barrier 2: sF reads done -> sP overlay writable

  // ---- epilogue: fwd+mirror, DPP quad reduction, 16 partials/pair ----
  uint32_t uJ[4][2];
#pragma unroll
  for (int r = 0; r < 4; ++r)
#pragma unroll
    for (int ni = 0; ni < 2; ++ni)
      uJ[r][ni] = sPP[(8 + (quad & 1) * 4 + r) * 132 + (wn2 * 2 + ni) * 16 + col];

#pragma unroll
  for (int mi = 0; mi < 4; ++mi) {
    const int ii = mi * 2 + (quad >> 1);
    uint32_t uI[2];
#pragma unroll
    for (int ni = 0; ni < 2; ++ni)
      uI[ni] = sPP[ii * 132 + (wn2 * 2 + ni) * 16 + col];
#pragma unroll
    for (int r = 0; r < 4; ++r) {
      int p = mi * 16 + quad * 4 + r;  // C/D: pair row = quad*4 + r
      uint4 sc = sScal[p];
      float f0 = ulo(sc.x), f1 = uhi(sc.x), f2 = ulo(sc.y), f3 = uhi(sc.y);
      float m0 = ulo(sc.z), m1 = uhi(sc.z), m2 = ulo(sc.w), m3 = uhi(sc.w);
      float vf = 0.f, vm = 0.f;
#pragma unroll
      for (int ni = 0; ni < 2; ++ni) {
        float piI = ulo(uI[ni]), pjI = uhi(uI[ni]);
        float piJ = ulo(uJ[r][ni]), pjJ = uhi(uJ[r][ni]);
        float a = acc[mi][ni][r];
        float pf = (a + piI) + pjJ;
        pf = fmaf(f0, cB0[ni], pf);
        pf = fmaf(f1, cB1[ni], pf);
        pf = fmaf(f2, cB2[ni], pf);
        pf = fmaf(f3, cB3[ni], pf);
        float pm = (a + piJ) + pjI;
        pm = fmaf(m0, cB0[ni], pm);
        pm = fmaf(m1, cB1[ni], pm);
        pm = fmaf(m2, cB2[ni], pm);
        pm = fmaf(m3, cB3[ni], pm);
        vf = fmaf(fmaxf(pf, 0.f), cW2[ni], vf);
        vm = fmaf(fmaxf(pm, 0.f), cW2[ni], vm);
      }
      vf = qsum4(vf);
      vm = qsum4(vm);
      if ((col & 3) == 0) {
        int part = wn2 * 4 + (col >> 2);
        sP[p * 42 + part] = vf;
        sP[p * 42 + 20 + part] = vm;
      }
    }
  }
  __syncthreads();  // barrier 3

  // ---- final: sum 16 fwd + 16 mirror partials, symmetric store ----
  if (tid < 64) {
    int p = tid;
    const float2* f2 = reinterpret_cast<const float2*>(sP + p * 42);
    const float2* m2 = reinterpret_cast<const float2*>(sP + p * 42 + 20);
    float sumF = 0.f, sumM = 0.f;
#pragma unroll
    for (int c = 0; c < 8; ++c) {
      float2 a = f2[c], d = m2[c];
      sumF += a.x + a.y;
      sumM += d.x + d.y;
    }
    float val = 0.5f * (sumF + sumM) + b2v;
    int iN = I0 + (p >> 3), jN = J0 + (p & 7);
    if (iN == jN) val = -1e9f;
    out[(size_t)(rowB + iN) * 256 + jN] = val;
    out[(size_t)(rowB + jN) * 256 + iN] = val;
  }
}

extern "C" void kernel_launch(void* const* d_in, const int* in_sizes, int n_in,
                              void* d_out, int out_size, void* d_ws, size_t ws_size,
                              hipStream_t stream) {
  const float* node = (const float*)d_in[0];   // [4,256,128]
  const float* baseL = (const float*)d_in[1];  // [4,256,256]
  const float* compL = (const float*)d_in[2];  // [4,256,256]
  const float* W1 = (const float*)d_in[3];     // [516,128]
  const float* b1 = (const float*)d_in[4];     // [128]
  const float* W2 = (const float*)d_in[5];     // [128,1]
  const float* b2 = (const float*)d_in[6];     // [1]
  float* out = (float*)d_out;                  // [4,256,256] fp32

  char* ws = (char*)d_ws;
  float* PiB = (float*)(ws);                        // 512 KB
  float* Pjf = (float*)(ws + (512 << 10));          // 512 KB
  uint32_t* W1f8 = (uint32_t*)(ws + (1024 << 10));  // 32 KB

  pre_k<<<288, 256, 0, stream>>>(node, W1, b1, PiB, Pjf, W1f8);
  main_k<<<2112, 256, 0, stream>>>(node, baseL, compL, W1, W2, b2, W1f8, PiB, Pjf, out);
}